// Round 13
// baseline (461.232 us; speedup 1.0000x reference)
//
#include <hip/hip_runtime.h>
#include <math.h>

#define H_ 152
#define W_ 272
#define HW_ 41344
#define W4_ 68       /* W_/4 */
#define HW4_ 10336   /* HW_/4 */
#define B_ 16
#define G_ 8
#define CG_ 16
#define NG_ 128   /* B*G */
#define PC_ 2048  /* NG*CG */
#define S_ 4
#define EPSV 1e-5f
#define NT2_ 81      /* ceil(HW4_/128) */

__device__ __forceinline__ float sigf(float v){ return 1.0f/(1.0f+__expf(-v)); }

// ---------------- Kernel 1: per-plane row means (xh) and col means (xw) ----
__global__ void k_stats1(const float* __restrict__ x, float* __restrict__ xh,
                         float* __restrict__ xw){
  int plane = blockIdx.x;
  const float* xp = x + (size_t)plane*HW_;
  int tid = threadIdx.x, wv = tid>>6, lane = tid&63;
  float ca0[4] = {0,0,0,0};
  float ca1[4] = {0,0,0,0};
  for (int h = wv; h < H_; h += 4){
    const float4* row = (const float4*)(xp + h*W_);
    float4 v0 = row[lane];
    float rs = v0.x+v0.y+v0.z+v0.w;
    ca0[0]+=v0.x; ca0[1]+=v0.y; ca0[2]+=v0.z; ca0[3]+=v0.w;
    if (lane < 4){
      float4 v1 = row[64+lane];
      rs += v1.x+v1.y+v1.z+v1.w;
      ca1[0]+=v1.x; ca1[1]+=v1.y; ca1[2]+=v1.z; ca1[3]+=v1.w;
    }
    #pragma unroll
    for (int off=32; off>0; off>>=1) rs += __shfl_down(rs, off, 64);
    if (lane==0) xh[plane*H_ + h] = rs * (1.0f/W_);
  }
  __shared__ float cs[4][W_];
  #pragma unroll
  for (int j=0;j<4;++j) cs[wv][lane*4+j] = ca0[j];
  if (lane<4){
    #pragma unroll
    for (int j=0;j<4;++j) cs[wv][256+lane*4+j] = ca1[j];
  }
  __syncthreads();
  for (int w=tid; w<W_; w+=256)
    xw[plane*W_ + w] = (cs[0][w]+cs[1][w]+cs[2][w]+cs[3][w]) * (1.0f/H_);
}

// ---------------- Kernel 2: sh/sw gates, x21 softmax, collapsed filter -----
__global__ void k_prep(const float* __restrict__ x,
                       const float* __restrict__ xh, const float* __restrict__ xw,
                       const float* __restrict__ w1, const float* __restrict__ b1,
                       const float* __restrict__ w3, const float* __restrict__ b3,
                       const float* __restrict__ gnb,
                       float* __restrict__ sh, float* __restrict__ sw,
                       float* __restrict__ x21, float* __restrict__ wsum,
                       float* __restrict__ bsum){
  int bg = blockIdx.x; int tid = threadIdx.x;
  __shared__ float xhl[CG_][H_];
  __shared__ float xwl[CG_][W_];
  __shared__ float w1l[CG_*CG_];
  __shared__ float b1l[CG_];
  __shared__ float Tk[CG_], R0[CG_], RL[CG_], C0[CG_], CL[CG_];
  __shared__ float crn[CG_][4];
  __shared__ float mx2[CG_], x11l[CG_];
  for (int i=tid;i<CG_*CG_;i+=256) w1l[i]=w1[i];
  if (tid < CG_) b1l[tid]=b1[tid];
  for (int i=tid;i<CG_*H_;i+=256){ int c=i/H_, h=i%H_; xhl[c][h]=xh[(bg*CG_+c)*H_+h]; }
  for (int i=tid;i<CG_*W_;i+=256){ int c=i/W_, w=i%W_; xwl[c][w]=xw[(bg*CG_+c)*W_+w]; }
  __syncthreads();
  // 1x1 conv + sigmoid on the row/col mean vectors
  for (int i=tid;i<CG_*H_;i+=256){
    int c=i/H_, h=i%H_;
    float a=b1l[c];
    #pragma unroll
    for (int k=0;k<CG_;++k) a += w1l[c*CG_+k]*xhl[k][h];
    sh[(bg*CG_+c)*H_+h] = sigf(a);
  }
  for (int i=tid;i<CG_*W_;i+=256){
    int c=i/W_, w=i%W_;
    float a=b1l[c];
    #pragma unroll
    for (int k=0;k<CG_;++k) a += w1l[c*CG_+k]*xwl[k][w];
    sw[(bg*CG_+c)*W_+w] = sigf(a);
  }
  // exact mean of 3x3-conv output via total/row/col/corner sums
  if (tid < CG_){
    int k=tid;
    float t=0;
    for (int h=0;h<H_;++h) t += xhl[k][h];
    Tk[k] = t * W_;
    R0[k] = xhl[k][0]*W_; RL[k]=xhl[k][H_-1]*W_;
    C0[k] = xwl[k][0]*H_; CL[k]=xwl[k][W_-1]*H_;
    const float* xp = x + (size_t)(bg*CG_+k)*HW_;
    crn[k][0]=xp[0]; crn[k][1]=xp[W_-1];
    crn[k][2]=xp[(size_t)(H_-1)*W_]; crn[k][3]=xp[(size_t)(H_-1)*W_+W_-1];
  }
  __syncthreads();
  if (tid < CG_){
    int c=tid;
    float acc=0;
    for (int k=0;k<CG_;++k){
      #pragma unroll
      for (int ky=0;ky<3;++ky){ int dy=ky-1;
        #pragma unroll
        for (int kx=0;kx<3;++kx){ int dx=kx-1;
          float s = Tk[k];
          if (dy==1) s -= R0[k]; else if (dy==-1) s -= RL[k];
          if (dx==1) s -= C0[k]; else if (dx==-1) s -= CL[k];
          if (dy==1 && dx==1) s += crn[k][0];
          else if (dy==1 && dx==-1) s += crn[k][1];
          else if (dy==-1 && dx==1) s += crn[k][2];
          else if (dy==-1 && dx==-1) s += crn[k][3];
          acc += w3[((c*CG_+k)*3+ky)*3+kx]*s;
        }
      }
    }
    mx2[c] = b3[c] + acc*(1.0f/HW_);
  }
  __syncthreads();
  if (tid==0){
    float m=mx2[0]; for (int c=1;c<CG_;++c) m=fmaxf(m,mx2[c]);
    float ssum=0.f; float e[CG_];
    for (int c=0;c<CG_;++c){ e[c]=__expf(mx2[c]-m); ssum+=e[c]; }
    for (int c=0;c<CG_;++c) x21[bg*CG_+c]=e[c]/ssum;
    // x11 = softmax(mean(x1)) = softmax(gn_b) exactly
    float m2=gnb[0]; for (int c=1;c<CG_;++c) m2=fmaxf(m2,gnb[c]);
    float s2=0.f; float e2[CG_];
    for (int c=0;c<CG_;++c){ e2[c]=__expf(gnb[c]-m2); s2+=e2[c]; }
    float bs=0.f;
    for (int c=0;c<CG_;++c){ x11l[c]=e2[c]/s2; bs += (e2[c]/s2)*b3[c]; }
    bsum[bg]=bs;
  }
  __syncthreads();
  for (int i=tid;i<CG_*9;i+=256){
    int k=i/9, r=i%9; int ky=r/3, kx=r%3;
    float a=0;
    for (int c=0;c<CG_;++c) a += x11l[c]*w3[((c*CG_+k)*3+ky)*3+kx];
    wsum[bg*CG_*9 + i] = a;
  }
}

// ---------------- Kernel 3: mu / rstd of pre = gx * sh * sw ---------------
__global__ void k_stats2(const float* __restrict__ x, const float* __restrict__ sh,
                         const float* __restrict__ sw, float* __restrict__ mu,
                         float* __restrict__ rstd){
  int plane = blockIdx.x; int tid=threadIdx.x;
  __shared__ float shl[H_]; __shared__ float swl[W_];
  for (int i=tid;i<H_;i+=256) shl[i]=sh[plane*H_+i];
  for (int i=tid;i<W_;i+=256) swl[i]=sw[plane*W_+i];
  __syncthreads();
  const float4* xp = (const float4*)(x + (size_t)plane*HW_);
  float s=0, s2=0;
  for (int i4=tid; i4<HW_/4; i4+=256){
    int p = i4*4; int h=p/W_, w=p%W_;
    float4 v = xp[i4];
    float shv = shl[h];
    float p0 = v.x*shv*swl[w], p1=v.y*shv*swl[w+1];
    float p2 = v.z*shv*swl[w+2], p3=v.w*shv*swl[w+3];
    s  += p0+p1+p2+p3;
    s2 += p0*p0+p1*p1+p2*p2+p3*p3;
  }
  __shared__ float rs[4], rs2[4];
  #pragma unroll
  for (int off=32; off>0; off>>=1){ s += __shfl_down(s,off,64); s2 += __shfl_down(s2,off,64); }
  int wv=tid>>6, lane=tid&63;
  if (lane==0){ rs[wv]=s; rs2[wv]=s2; }
  __syncthreads();
  if (tid==0){
    float S1=rs[0]+rs[1]+rs[2]+rs[3], S2=rs2[0]+rs2[1]+rs2[2]+rs2[3];
    float m = S1*(1.0f/HW_);
    float v = S2*(1.0f/HW_)-m*m;
    mu[plane]=m; rstd[plane]=rsqrtf(v+EPSV);
  }
}

// ---------------- Kernel 4: alpha and weight constant ---------------------
__global__ void k_coef(const float* __restrict__ x21, const float* __restrict__ gnw,
                       const float* __restrict__ gnb, const float* __restrict__ mu,
                       const float* __restrict__ rstd, const float* __restrict__ bsum,
                       float* __restrict__ alpha, float* __restrict__ wconst){
  int bg = blockIdx.x; int tid=threadIdx.x;
  float contrib = 0.f;
  if (tid < CG_){
    int plane = bg*CG_+tid;
    float t21 = x21[plane];
    alpha[plane] = t21*gnw[tid]*rstd[plane];
    contrib = t21*(gnb[tid] - mu[plane]*rstd[plane]*gnw[tid]);
  }
  #pragma unroll
  for (int off=8; off>0; off>>=1) contrib += __shfl_down(contrib, off, 64);
  if (tid==0) wconst[bg] = bsum[bg] + contrib;
}

// ---------------- Kernel 5: dual-slot 4-wave channel-split + fused out ----
// Each thread owns TWO independent float4 slots (i4, i4+64): two dependence
// chains per channel iteration double memory-level parallelism at ~+24 live
// regs (still <=64: no spill). Rolled channel loop; XCD swizzle; shfl edges;
// LDS coefficient staging; LDS partial-sum exchange.
__global__ void k_weights(const float* __restrict__ x, const float* __restrict__ sh,
                          const float* __restrict__ sw, const float* __restrict__ alpha,
                          const float* __restrict__ wsum, const float* __restrict__ wconst,
                          float* __restrict__ wout, float* __restrict__ out){
  int wgid = blockIdx.x + blockIdx.y*gridDim.x;        // dispatch order (x fastest)
  int swz  = (wgid & 7)*(NT2_*NG_/8) + (wgid >> 3);    // bijective: 10368%8==0
  int bg   = swz / NT2_;
  int tile = swz % NT2_;
  int tid = threadIdx.x;
  int ty = tid>>6, lane = tid&63;
  int i4a = tile*128 + lane;           // always < HW4_ (81*128-65 < 10336+64)
  int i4b = i4a + 64;
  bool oka = (i4a < HW4_);
  bool okb = (i4b < HW4_);
  int ia = oka ? i4a : (HW4_-1);
  int ib = okb ? i4b : (HW4_-1);
  int w4a = ia % W4_, ha = ia / W4_, pa = ia*4;
  int w4b = ib % W4_, hb = ib / W4_, pb = ib*4;
  bool hma=(ha>0), hpa=(ha<H_-1), wma=(w4a>0), wpa=(w4a<W4_-1);
  bool hmb=(hb>0), hpb=(hb<H_-1), wmb=(w4b>0), wpb=(w4b<W4_-1);
  const float4 z4 = {0.f,0.f,0.f,0.f};

  // ---- stage per-block coefficients into LDS ----
  __shared__ float wsl[CG_*9];
  __shared__ float all[CG_];
  __shared__ float shl[CG_][3];
  int h0 = (tile*128) / W4_;           // block spans h0 .. h0+2 at most
  if (tid < CG_*9) wsl[tid] = wsum[bg*CG_*9 + tid];
  else if (tid < CG_*9 + CG_) all[tid - CG_*9] = alpha[bg*CG_ + (tid - CG_*9)];
  else if (tid < CG_*9 + CG_ + 3*CG_){
    int t = tid - CG_*9 - CG_;
    int c = t/3, r = t%3;
    int hh = h0 + r; if (hh > H_-1) hh = H_-1;
    shl[c][r] = sh[(bg*CG_+c)*H_ + hh];
  }
  __syncthreads();

  float4 accA = z4, accB = z4;
  #pragma unroll 1
  for (int j=0;j<4;++j){
    int c = ty*4 + j;
    const float* xp  = x  + (size_t)(bg*CG_+c)*HW_;
    // ---- slot A loads ----
    float4 v0a = *(const float4*)(xp + pa);
    float4 vma = hma ? *(const float4*)(xp + pa - W_) : z4;
    float4 vpa = hpa ? *(const float4*)(xp + pa + W_) : z4;
    float4 swva = *(const float4*)(&sw[(bg*CG_+c)*W_ + w4a*4]);
    // ---- slot B loads (independent chain) ----
    float4 v0b = *(const float4*)(xp + pb);
    float4 vmb = hmb ? *(const float4*)(xp + pb - W_) : z4;
    float4 vpb = hpb ? *(const float4*)(xp + pb + W_) : z4;
    float4 swvb = *(const float4*)(&sw[(bg*CG_+c)*W_ + w4b*4]);
    // ---- slot A edges via shuffles ----
    float lma = __shfl_up(vma.w, 1, 64);
    float l0a = __shfl_up(v0a.w, 1, 64);
    float lpa = __shfl_up(vpa.w, 1, 64);
    float rma = __shfl_down(vma.x, 1, 64);
    float r0a = __shfl_down(v0a.x, 1, 64);
    float rpa = __shfl_down(vpa.x, 1, 64);
    if (!wma){ lma=0.f; l0a=0.f; lpa=0.f; }
    if (!wpa){ rma=0.f; r0a=0.f; rpa=0.f; }
    if (lane==0 || lane==63){
      bool L = (lane==0);
      bool en = L ? wma : wpa;
      int q = L ? (pa-1) : (pa+4);
      float em = (en&&hma) ? xp[q-W_] : 0.f;
      float e0 = en         ? xp[q]    : 0.f;
      float ep = (en&&hpa) ? xp[q+W_] : 0.f;
      if (L){ lma=em; l0a=e0; lpa=ep; } else { rma=em; r0a=e0; rpa=ep; }
    }
    // ---- slot B edges via shuffles ----
    float lmb = __shfl_up(vmb.w, 1, 64);
    float l0b = __shfl_up(v0b.w, 1, 64);
    float lpb = __shfl_up(vpb.w, 1, 64);
    float rmb = __shfl_down(vmb.x, 1, 64);
    float r0b = __shfl_down(v0b.x, 1, 64);
    float rpb = __shfl_down(vpb.x, 1, 64);
    if (!wmb){ lmb=0.f; l0b=0.f; lpb=0.f; }
    if (!wpb){ rmb=0.f; r0b=0.f; rpb=0.f; }
    if (lane==0 || lane==63){
      bool L = (lane==0);
      bool en = L ? wmb : wpb;
      int q = L ? (pb-1) : (pb+4);
      float em = (en&&hmb) ? xp[q-W_] : 0.f;
      float e0 = en         ? xp[q]    : 0.f;
      float ep = (en&&hpb) ? xp[q+W_] : 0.f;
      if (L){ lmb=em; l0b=e0; lpb=ep; } else { rmb=em; r0b=e0; rpb=ep; }
    }
    const float* wr = wsl + c*9;
    float w0=wr[0], w1v=wr[1], w2=wr[2], w3v=wr[3], w4v=wr[4];
    float w5=wr[5], w6=wr[6], w7=wr[7], w8=wr[8];
    float aA = all[c] * shl[c][ha - h0];
    float aB = all[c] * shl[c][hb - h0];
    // ---- slot A FMAs ----
    accA.x += aA*swva.x*v0a.x + w0*lma   + w1v*vma.x + w2*vma.y
            + w3v*l0a         + w4v*v0a.x + w5*v0a.y
            + w6*lpa          + w7*vpa.x + w8*vpa.y;
    accA.y += aA*swva.y*v0a.y + w0*vma.x + w1v*vma.y + w2*vma.z
            + w3v*v0a.x       + w4v*v0a.y + w5*v0a.z
            + w6*vpa.x        + w7*vpa.y + w8*vpa.z;
    accA.z += aA*swva.z*v0a.z + w0*vma.y + w1v*vma.z + w2*vma.w
            + w3v*v0a.y       + w4v*v0a.z + w5*v0a.w
            + w6*vpa.y        + w7*vpa.z + w8*vpa.w;
    accA.w += aA*swva.w*v0a.w + w0*vma.z + w1v*vma.w + w2*rma
            + w3v*v0a.z       + w4v*v0a.w + w5*r0a
            + w6*vpa.z        + w7*vpa.w + w8*rpa;
    // ---- slot B FMAs ----
    accB.x += aB*swvb.x*v0b.x + w0*lmb   + w1v*vmb.x + w2*vmb.y
            + w3v*l0b         + w4v*v0b.x + w5*v0b.y
            + w6*lpb          + w7*vpb.x + w8*vpb.y;
    accB.y += aB*swvb.y*v0b.y + w0*vmb.x + w1v*vmb.y + w2*vmb.z
            + w3v*v0b.x       + w4v*v0b.y + w5*v0b.z
            + w6*vpb.x        + w7*vpb.y + w8*vpb.z;
    accB.z += aB*swvb.z*v0b.z + w0*vmb.y + w1v*vmb.z + w2*vmb.w
            + w3v*v0b.y       + w4v*v0b.z + w5*v0b.w
            + w6*vpb.y        + w7*vpb.z + w8*vpb.w;
    accB.w += aB*swvb.w*v0b.w + w0*vmb.z + w1v*vmb.w + w2*rmb
            + w3v*v0b.z       + w4v*v0b.w + w5*r0b
            + w6*vpb.z        + w7*vpb.w + w8*rpb;
  }

  __shared__ float4 part[4][128];
  part[ty][lane]    = accA;
  part[ty][64+lane] = accB;
  __syncthreads();

  float wc = wconst[bg];
  float4 totA, totB;
  {
    float4 q0 = part[0][lane], q1 = part[1][lane];
    float4 q2 = part[2][lane], q3 = part[3][lane];
    totA.x = q0.x+q1.x+q2.x+q3.x + wc;
    totA.y = q0.y+q1.y+q2.y+q3.y + wc;
    totA.z = q0.z+q1.z+q2.z+q3.z + wc;
    totA.w = q0.w+q1.w+q2.w+q3.w + wc;
  }
  {
    float4 q0 = part[0][64+lane], q1 = part[1][64+lane];
    float4 q2 = part[2][64+lane], q3 = part[3][64+lane];
    totB.x = q0.x+q1.x+q2.x+q3.x + wc;
    totB.y = q0.y+q1.y+q2.y+q3.y + wc;
    totB.z = q0.z+q1.z+q2.z+q3.z + wc;
    totB.w = q0.w+q1.w+q2.w+q3.w + wc;
  }

  if (ty==0){
    if (oka) *(float4*)(wout + (size_t)bg*HW_ + pa) = totA;
    if (okb) *(float4*)(wout + (size_t)bg*HW_ + pb) = totB;
  }

  float4 gvA, gvB;
  gvA.x = sigf(totA.x); gvA.y = sigf(totA.y); gvA.z = sigf(totA.z); gvA.w = sigf(totA.w);
  gvB.x = sigf(totB.x); gvB.y = sigf(totB.y); gvB.z = sigf(totB.z); gvB.w = sigf(totB.w);
  int b = bg>>3, g = bg&7;
  #pragma unroll 1
  for (int j=0;j<4;++j){
    int c = ty*4 + j;
    const float* xp = x + (size_t)(bg*CG_+c)*HW_;
    float* ob = out + (size_t)(b*128 + c*8 + g)*HW_;
    if (oka){
      float4 cv = *(const float4*)(xp + pa);   // L1/L2-hot reload
      float4 o; float s;
      s = cv.x*gvA.x; o.x = cv.x + s*sigf(s);
      s = cv.y*gvA.y; o.y = cv.y + s*sigf(s);
      s = cv.z*gvA.z; o.z = cv.z + s*sigf(s);
      s = cv.w*gvA.w; o.w = cv.w + s*sigf(s);
      *(float4*)(ob + pa) = o;
    }
    if (okb){
      float4 cv = *(const float4*)(xp + pb);
      float4 o; float s;
      s = cv.x*gvB.x; o.x = cv.x + s*sigf(s);
      s = cv.y*gvB.y; o.y = cv.y + s*sigf(s);
      s = cv.z*gvB.z; o.z = cv.z + s*sigf(s);
      s = cv.w*gvB.w; o.w = cv.w + s*sigf(s);
      *(float4*)(ob + pb) = o;
    }
  }
}

// ---------------- Kernel 6: detection-region conv fixup -------------------
// one block per (b, idx, co): 2048 blocks x 64 threads
__global__ void k_fix(const float* __restrict__ x, const float* __restrict__ wout,
                      const int* __restrict__ det,
                      const float* __restrict__ cw0, const float* __restrict__ cb0,
                      const float* __restrict__ cw1, const float* __restrict__ cb1,
                      const float* __restrict__ cw2, const float* __restrict__ cb2,
                      const float* __restrict__ cw3, const float* __restrict__ cb3,
                      float* __restrict__ out){
  int blk = blockIdx.x;
  int co = blk & 31;
  int bi = blk >> 5;
  int b = bi>>2, idx = bi&3;
  int cx = det[(b*S_+idx)*4+0], cy = det[(b*S_+idx)*4+1];
  if (!(cy>=2 && cy<H_-2 && cx>=2 && cx<W_-2)) return;   // uniform per block
  int ys = cy-2, xs = cx-2;  // in-bounds given validity
  int k = 2*idx+3, pad = idx+1, kk = k*k;
  const float* cw = idx==0?cw0: idx==1?cw1: idx==2?cw2:cw3;
  const float* cb = idx==0?cb0: idx==1?cb1: idx==2?cb2:cb3;
  __shared__ float reg[32*25];
  __shared__ float wl[32*81];
  int tid = threadIdx.x;
  for (int t=tid;t<800;t+=64){
    int ci=t/25, r=t%25, ry=r/5, rx=r%5;
    int g = idx*2 + (ci>>4), cg = ci&15;
    int bg = b*G_+g; int plane = bg*CG_+cg;
    int p = (ys+ry)*W_ + xs+rx;
    reg[t] = x[(size_t)plane*HW_+p]*sigf(wout[(size_t)bg*HW_+p]);
  }
  for (int t=tid;t<32*kk;t+=64) wl[t] = cw[co*32*kk + t];
  __syncthreads();
  // lanes 0..24: pixels, ci 0..15 ; lanes 25..49: same pixels, ci 16..31
  int pix = (tid<25)?tid:(tid-25);
  int half = (tid<25)?0:1;
  float acc = 0.f;
  if (tid < 50){
    int oy = pix/5, ox = pix%5;
    for (int ci=half*16; ci<half*16+16; ++ci){
      const float* wr = wl + ci*kk;
      const float* rr = reg + ci*25;
      #pragma unroll
      for (int iy=0; iy<5; ++iy){
        int ky = iy-oy+pad;
        if ((unsigned)ky >= (unsigned)k) continue;
        #pragma unroll
        for (int ix=0; ix<5; ++ix){
          int kx = ix-ox+pad;
          if ((unsigned)kx >= (unsigned)k) continue;
          acc += wr[ky*k+kx]*rr[iy*5+ix];
        }
      }
    }
  }
  float other = __shfl(acc, tid+25, 64);
  if (tid < 25){
    float tot = cb[co] + acc + other;
    int oy = pix/5, ox = pix%5;
    int g = idx*2 + (co>>4), cg = co&15;
    int bg = b*G_+g; int plane = bg*CG_+cg;
    int p = (ys+oy)*W_ + xs+ox;
    float xv = x[(size_t)plane*HW_+p];
    out[(size_t)(b*128 + cg*8 + g)*HW_+p] = xv + tot*sigf(tot);
  }
}

extern "C" void kernel_launch(void* const* d_in, const int* in_sizes, int n_in,
                              void* d_out, int out_size, void* d_ws, size_t ws_size,
                              hipStream_t stream){
  const float* x   = (const float*)d_in[0];
  const int*   det = (const int*)d_in[1];
  const float* w1  = (const float*)d_in[2];
  const float* b1  = (const float*)d_in[3];
  const float* w3  = (const float*)d_in[4];
  const float* b3  = (const float*)d_in[5];
  const float* gnw = (const float*)d_in[6];
  const float* gnb = (const float*)d_in[7];
  const float* cw0 = (const float*)d_in[8];  const float* cb0 = (const float*)d_in[9];
  const float* cw1 = (const float*)d_in[10]; const float* cb1 = (const float*)d_in[11];
  const float* cw2 = (const float*)d_in[12]; const float* cb2 = (const float*)d_in[13];
  const float* cw3 = (const float*)d_in[14]; const float* cb3 = (const float*)d_in[15];

  float* ws = (float*)d_ws;
  float* xh    = ws;                 // PC_*H_
  float* xw    = xh + PC_*H_;        // PC_*W_
  float* sh    = xw + PC_*W_;        // PC_*H_
  float* sw    = sh + PC_*H_;        // PC_*W_
  float* mu    = sw + PC_*W_;        // PC_
  float* rstd  = mu + PC_;           // PC_
  float* x21   = rstd + PC_;         // PC_
  float* alpha = x21 + PC_;          // PC_
  float* wsum  = alpha + PC_;        // NG_*144
  float* bsum  = wsum + NG_*144;     // NG_
  float* wconst= bsum + NG_;         // NG_
  float* wout  = wconst + NG_;       // NG_*HW_
  float* outp  = (float*)d_out;

  k_stats1<<<PC_,256,0,stream>>>(x, xh, xw);
  k_prep<<<NG_,256,0,stream>>>(x, xh, xw, w1,b1,w3,b3,gnb, sh,sw,x21,wsum,bsum);
  k_stats2<<<PC_,256,0,stream>>>(x, sh, sw, mu, rstd);
  k_coef<<<NG_,64,0,stream>>>(x21,gnw,gnb,mu,rstd,bsum,alpha,wconst);
  dim3 gw(NT2_, NG_);   // 128 float4-slots per block; swizzled inside
  k_weights<<<gw,256,0,stream>>>(x, sh, sw, alpha, wsum, wconst, wout, outp);
  k_fix<<<B_*S_*32,64,0,stream>>>(x, wout, det, cw0,cb0,cw1,cb1,cw2,cb2,cw3,cb3, outp);
}

// Round 14
// 396.063 us; speedup vs baseline: 1.1645x; 1.1645x over previous
//
#include <hip/hip_runtime.h>
#include <math.h>

#define H_ 152
#define W_ 272
#define HW_ 41344
#define W4_ 68       /* W_/4 */
#define HW4_ 10336   /* HW_/4 */
#define B_ 16
#define G_ 8
#define CG_ 16
#define NG_ 128   /* B*G */
#define PC_ 2048  /* NG*CG */
#define S_ 4
#define EPSV 1e-5f
#define NTILE_ 162   /* ceil(HW4_/64) */

__device__ __forceinline__ float sigf(float v){ return 1.0f/(1.0f+__expf(-v)); }

// ---------------- Kernel 1: per-plane row means (xh) and col means (xw) ----
__global__ void k_stats1(const float* __restrict__ x, float* __restrict__ xh,
                         float* __restrict__ xw){
  int plane = blockIdx.x;
  const float* xp = x + (size_t)plane*HW_;
  int tid = threadIdx.x, wv = tid>>6, lane = tid&63;
  float ca0[4] = {0,0,0,0};
  float ca1[4] = {0,0,0,0};
  for (int h = wv; h < H_; h += 4){
    const float4* row = (const float4*)(xp + h*W_);
    float4 v0 = row[lane];
    float rs = v0.x+v0.y+v0.z+v0.w;
    ca0[0]+=v0.x; ca0[1]+=v0.y; ca0[2]+=v0.z; ca0[3]+=v0.w;
    if (lane < 4){
      float4 v1 = row[64+lane];
      rs += v1.x+v1.y+v1.z+v1.w;
      ca1[0]+=v1.x; ca1[1]+=v1.y; ca1[2]+=v1.z; ca1[3]+=v1.w;
    }
    #pragma unroll
    for (int off=32; off>0; off>>=1) rs += __shfl_down(rs, off, 64);
    if (lane==0) xh[plane*H_ + h] = rs * (1.0f/W_);
  }
  __shared__ float cs[4][W_];
  #pragma unroll
  for (int j=0;j<4;++j) cs[wv][lane*4+j] = ca0[j];
  if (lane<4){
    #pragma unroll
    for (int j=0;j<4;++j) cs[wv][256+lane*4+j] = ca1[j];
  }
  __syncthreads();
  for (int w=tid; w<W_; w+=256)
    xw[plane*W_ + w] = (cs[0][w]+cs[1][w]+cs[2][w]+cs[3][w]) * (1.0f/H_);
}

// ---------------- Kernel 2: sh/sw gates, x21 softmax, collapsed filter -----
__global__ void k_prep(const float* __restrict__ x,
                       const float* __restrict__ xh, const float* __restrict__ xw,
                       const float* __restrict__ w1, const float* __restrict__ b1,
                       const float* __restrict__ w3, const float* __restrict__ b3,
                       const float* __restrict__ gnb,
                       float* __restrict__ sh, float* __restrict__ sw,
                       float* __restrict__ x21, float* __restrict__ wsum,
                       float* __restrict__ bsum){
  int bg = blockIdx.x; int tid = threadIdx.x;
  __shared__ float xhl[CG_][H_];
  __shared__ float xwl[CG_][W_];
  __shared__ float w1l[CG_*CG_];
  __shared__ float b1l[CG_];
  __shared__ float Tk[CG_], R0[CG_], RL[CG_], C0[CG_], CL[CG_];
  __shared__ float crn[CG_][4];
  __shared__ float mx2[CG_], x11l[CG_];
  for (int i=tid;i<CG_*CG_;i+=256) w1l[i]=w1[i];
  if (tid < CG_) b1l[tid]=b1[tid];
  for (int i=tid;i<CG_*H_;i+=256){ int c=i/H_, h=i%H_; xhl[c][h]=xh[(bg*CG_+c)*H_+h]; }
  for (int i=tid;i<CG_*W_;i+=256){ int c=i/W_, w=i%W_; xwl[c][w]=xw[(bg*CG_+c)*W_+w]; }
  __syncthreads();
  // 1x1 conv + sigmoid on the row/col mean vectors
  for (int i=tid;i<CG_*H_;i+=256){
    int c=i/H_, h=i%H_;
    float a=b1l[c];
    #pragma unroll
    for (int k=0;k<CG_;++k) a += w1l[c*CG_+k]*xhl[k][h];
    sh[(bg*CG_+c)*H_+h] = sigf(a);
  }
  for (int i=tid;i<CG_*W_;i+=256){
    int c=i/W_, w=i%W_;
    float a=b1l[c];
    #pragma unroll
    for (int k=0;k<CG_;++k) a += w1l[c*CG_+k]*xwl[k][w];
    sw[(bg*CG_+c)*W_+w] = sigf(a);
  }
  // exact mean of 3x3-conv output via total/row/col/corner sums
  if (tid < CG_){
    int k=tid;
    float t=0;
    for (int h=0;h<H_;++h) t += xhl[k][h];
    Tk[k] = t * W_;
    R0[k] = xhl[k][0]*W_; RL[k]=xhl[k][H_-1]*W_;
    C0[k] = xwl[k][0]*H_; CL[k]=xwl[k][W_-1]*H_;
    const float* xp = x + (size_t)(bg*CG_+k)*HW_;
    crn[k][0]=xp[0]; crn[k][1]=xp[W_-1];
    crn[k][2]=xp[(size_t)(H_-1)*W_]; crn[k][3]=xp[(size_t)(H_-1)*W_+W_-1];
  }
  __syncthreads();
  if (tid < CG_){
    int c=tid;
    float acc=0;
    for (int k=0;k<CG_;++k){
      #pragma unroll
      for (int ky=0;ky<3;++ky){ int dy=ky-1;
        #pragma unroll
        for (int kx=0;kx<3;++kx){ int dx=kx-1;
          float s = Tk[k];
          if (dy==1) s -= R0[k]; else if (dy==-1) s -= RL[k];
          if (dx==1) s -= C0[k]; else if (dx==-1) s -= CL[k];
          if (dy==1 && dx==1) s += crn[k][0];
          else if (dy==1 && dx==-1) s += crn[k][1];
          else if (dy==-1 && dx==1) s += crn[k][2];
          else if (dy==-1 && dx==-1) s += crn[k][3];
          acc += w3[((c*CG_+k)*3+ky)*3+kx]*s;
        }
      }
    }
    mx2[c] = b3[c] + acc*(1.0f/HW_);
  }
  __syncthreads();
  if (tid==0){
    float m=mx2[0]; for (int c=1;c<CG_;++c) m=fmaxf(m,mx2[c]);
    float ssum=0.f; float e[CG_];
    for (int c=0;c<CG_;++c){ e[c]=__expf(mx2[c]-m); ssum+=e[c]; }
    for (int c=0;c<CG_;++c) x21[bg*CG_+c]=e[c]/ssum;
    // x11 = softmax(mean(x1)) = softmax(gn_b) exactly
    float m2=gnb[0]; for (int c=1;c<CG_;++c) m2=fmaxf(m2,gnb[c]);
    float s2=0.f; float e2[CG_];
    for (int c=0;c<CG_;++c){ e2[c]=__expf(gnb[c]-m2); s2+=e2[c]; }
    float bs=0.f;
    for (int c=0;c<CG_;++c){ x11l[c]=e2[c]/s2; bs += (e2[c]/s2)*b3[c]; }
    bsum[bg]=bs;
  }
  __syncthreads();
  for (int i=tid;i<CG_*9;i+=256){
    int k=i/9, r=i%9; int ky=r/3, kx=r%3;
    float a=0;
    for (int c=0;c<CG_;++c) a += x11l[c]*w3[((c*CG_+k)*3+ky)*3+kx];
    wsum[bg*CG_*9 + i] = a;
  }
}

// ---------------- Kernel 3: mu / rstd of pre = gx * sh * sw ---------------
__global__ void k_stats2(const float* __restrict__ x, const float* __restrict__ sh,
                         const float* __restrict__ sw, float* __restrict__ mu,
                         float* __restrict__ rstd){
  int plane = blockIdx.x; int tid=threadIdx.x;
  __shared__ float shl[H_]; __shared__ float swl[W_];
  for (int i=tid;i<H_;i+=256) shl[i]=sh[plane*H_+i];
  for (int i=tid;i<W_;i+=256) swl[i]=sw[plane*W_+i];
  __syncthreads();
  const float4* xp = (const float4*)(x + (size_t)plane*HW_);
  float s=0, s2=0;
  for (int i4=tid; i4<HW_/4; i4+=256){
    int p = i4*4; int h=p/W_, w=p%W_;
    float4 v = xp[i4];
    float shv = shl[h];
    float p0 = v.x*shv*swl[w], p1=v.y*shv*swl[w+1];
    float p2 = v.z*shv*swl[w+2], p3=v.w*shv*swl[w+3];
    s  += p0+p1+p2+p3;
    s2 += p0*p0+p1*p1+p2*p2+p3*p3;
  }
  __shared__ float rs[4], rs2[4];
  #pragma unroll
  for (int off=32; off>0; off>>=1){ s += __shfl_down(s,off,64); s2 += __shfl_down(s2,off,64); }
  int wv=tid>>6, lane=tid&63;
  if (lane==0){ rs[wv]=s; rs2[wv]=s2; }
  __syncthreads();
  if (tid==0){
    float S1=rs[0]+rs[1]+rs[2]+rs[3], S2=rs2[0]+rs2[1]+rs2[2]+rs2[3];
    float m = S1*(1.0f/HW_);
    float v = S2*(1.0f/HW_)-m*m;
    mu[plane]=m; rstd[plane]=rsqrtf(v+EPSV);
  }
}

// ---------------- Kernel 4: alpha and weight constant ---------------------
__global__ void k_coef(const float* __restrict__ x21, const float* __restrict__ gnw,
                       const float* __restrict__ gnb, const float* __restrict__ mu,
                       const float* __restrict__ rstd, const float* __restrict__ bsum,
                       float* __restrict__ alpha, float* __restrict__ wconst){
  int bg = blockIdx.x; int tid=threadIdx.x;
  float contrib = 0.f;
  if (tid < CG_){
    int plane = bg*CG_+tid;
    float t21 = x21[plane];
    alpha[plane] = t21*gnw[tid]*rstd[plane];
    contrib = t21*(gnb[tid] - mu[plane]*rstd[plane]*gnw[tid]);
  }
  #pragma unroll
  for (int off=8; off>0; off>>=1) contrib += __shfl_down(contrib, off, 64);
  if (tid==0) wconst[bg] = bsum[bg] + contrib;
}

// ---------------- Kernel 5: 4-wave channel-split weight map + fused out ---
// r12 structure (rolled channel loop, XCD swizzle, shfl edges, LDS coeff
// staging, LDS partial-sum exchange) + cross-iteration PREFETCH of the next
// channel's 4 wide loads into NAMED float4s (no arrays/structs -> SROA-safe,
// ~52 live regs, below the 64 spill cliff). The vmcnt wait for the prefetch
// lands at the bottom rotation copies, after the current channel's FMAs.
__global__ void k_weights(const float* __restrict__ x, const float* __restrict__ sh,
                          const float* __restrict__ sw, const float* __restrict__ alpha,
                          const float* __restrict__ wsum, const float* __restrict__ wconst,
                          float* __restrict__ wout, float* __restrict__ out){
  int wgid = blockIdx.x + blockIdx.y*gridDim.x;        // dispatch order (x fastest)
  int swz  = (wgid & 7)*(NTILE_*NG_/8) + (wgid >> 3);  // bijective: 20736%8==0
  int bg   = swz / NTILE_;
  int tile = swz % NTILE_;
  int tid = threadIdx.x;
  int ty = tid>>6, lane = tid&63;
  int i4 = tile*64 + lane;
  bool ok = (i4 < HW4_);
  int i4c = ok ? i4 : (HW4_-1);          // clamped for safe addresses
  int w4 = i4c % W4_, h = i4c / W4_;
  int p  = i4c*4;
  bool hm=(h>0), hp=(h<H_-1), wm=(w4>0), wp=(w4<W4_-1);
  const float4 z4 = {0.f,0.f,0.f,0.f};

  // ---- stage per-block coefficients into LDS ----
  __shared__ float wsl[CG_*9];
  __shared__ float all[CG_];
  __shared__ float shl[CG_][2];
  int h0 = (tile*64) / W4_;              // block spans h0 .. h0+1 at most
  if (tid < CG_*9) wsl[tid] = wsum[bg*CG_*9 + tid];
  else if (tid < CG_*9 + CG_) all[tid - CG_*9] = alpha[bg*CG_ + (tid - CG_*9)];
  else if (tid < CG_*9 + CG_ + 2*CG_){
    int t = tid - CG_*9 - CG_;
    int c = t>>1, r = t&1;
    int hh = h0 + r; if (hh > H_-1) hh = H_-1;
    shl[c][r] = sh[(bg*CG_+c)*H_ + hh];
  }
  __syncthreads();

  float4 acc = z4;
  // prime the pipeline with channel ty*4
  const float* xp0 = x + (size_t)(bg*CG_ + ty*4)*HW_;
  float4 v0 = *(const float4*)(xp0 + p);
  float4 vm = hm ? *(const float4*)(xp0 + p - W_) : z4;
  float4 vp = hp ? *(const float4*)(xp0 + p + W_) : z4;
  float4 swv = *(const float4*)(&sw[(bg*CG_ + ty*4)*W_ + w4*4]);

  #pragma unroll 1
  for (int j=0;j<4;++j){
    int c = ty*4 + j;
    const float* xp = x + (size_t)(bg*CG_+c)*HW_;
    // ---- prefetch channel c+1 (issued before current FMAs) ----
    float4 n0=z4, nm=z4, np=z4, nsw=z4;
    if (j<3){
      const float* xn = xp + HW_;
      n0 = *(const float4*)(xn + p);
      nm = hm ? *(const float4*)(xn + p - W_) : z4;
      np = hp ? *(const float4*)(xn + p + W_) : z4;
      nsw = *(const float4*)(&sw[(bg*CG_+c+1)*W_ + w4*4]);
    }
    // ---- edges from neighbor lanes' registers (data already resident) ----
    float lm = __shfl_up(vm.w, 1, 64);
    float l0 = __shfl_up(v0.w, 1, 64);
    float lp = __shfl_up(vp.w, 1, 64);
    float rm = __shfl_down(vm.x, 1, 64);
    float r0 = __shfl_down(v0.x, 1, 64);
    float rp = __shfl_down(vp.x, 1, 64);
    if (!wm){ lm=0.f; l0=0.f; lp=0.f; }
    if (!wp){ rm=0.f; r0=0.f; rp=0.f; }
    if (lane==0 || lane==63){
      bool L = (lane==0);
      bool en = L ? wm : wp;
      int q = L ? (p-1) : (p+4);
      float em = (en&&hm) ? xp[q-W_] : 0.f;
      float e0 = en        ? xp[q]    : 0.f;
      float ep = (en&&hp) ? xp[q+W_] : 0.f;
      if (L){ lm=em; l0=e0; lp=ep; } else { rm=em; r0=e0; rp=ep; }
    }
    float a = all[c] * shl[c][h - h0];
    const float* wr = wsl + c*9;
    float w0=wr[0], w1v=wr[1], w2=wr[2], w3v=wr[3], w4v=wr[4];
    float w5=wr[5], w6=wr[6], w7=wr[7], w8=wr[8];
    acc.x += a*swv.x*v0.x + w0*lm   + w1v*vm.x + w2*vm.y
           + w3v*l0       + w4v*v0.x + w5*v0.y
           + w6*lp        + w7*vp.x + w8*vp.y;
    acc.y += a*swv.y*v0.y + w0*vm.x + w1v*vm.y + w2*vm.z
           + w3v*v0.x     + w4v*v0.y + w5*v0.z
           + w6*vp.x      + w7*vp.y + w8*vp.z;
    acc.z += a*swv.z*v0.z + w0*vm.y + w1v*vm.z + w2*vm.w
           + w3v*v0.y     + w4v*v0.z + w5*v0.w
           + w6*vp.y      + w7*vp.z + w8*vp.w;
    acc.w += a*swv.w*v0.w + w0*vm.z + w1v*vm.w + w2*rm
           + w3v*v0.z     + w4v*v0.w + w5*r0
           + w6*vp.z      + w7*vp.w + w8*rp;
    // ---- rotate (vmcnt wait lands here, after the FMAs) ----
    v0 = n0; vm = nm; vp = np; swv = nsw;
  }

  __shared__ float4 part[4][64];
  part[ty][lane] = acc;
  __syncthreads();

  float4 p0v = part[0][lane], p1v = part[1][lane];
  float4 p2v = part[2][lane], p3v = part[3][lane];
  float wc = wconst[bg];
  float4 tot;
  tot.x = p0v.x+p1v.x+p2v.x+p3v.x + wc;
  tot.y = p0v.y+p1v.y+p2v.y+p3v.y + wc;
  tot.z = p0v.z+p1v.z+p2v.z+p3v.z + wc;
  tot.w = p0v.w+p1v.w+p2v.w+p3v.w + wc;

  if (ty==0 && ok) *(float4*)(wout + (size_t)bg*HW_ + p) = tot;

  float4 gv;
  gv.x = sigf(tot.x); gv.y = sigf(tot.y); gv.z = sigf(tot.z); gv.w = sigf(tot.w);
  int b = bg>>3, g = bg&7;
  if (ok){
    #pragma unroll 1
    for (int j=0;j<4;++j){
      int c = ty*4 + j;
      const float* xp = x + (size_t)(bg*CG_+c)*HW_;
      float4 cv = *(const float4*)(xp + p);   // L1/L2-hot reload
      float* ob = out + (size_t)(b*128 + c*8 + g)*HW_ + p;
      float4 o; float s;
      s = cv.x*gv.x; o.x = cv.x + s*sigf(s);
      s = cv.y*gv.y; o.y = cv.y + s*sigf(s);
      s = cv.z*gv.z; o.z = cv.z + s*sigf(s);
      s = cv.w*gv.w; o.w = cv.w + s*sigf(s);
      *(float4*)ob = o;
    }
  }
}

// ---------------- Kernel 6: detection-region conv fixup -------------------
// one block per (b, idx, co): 2048 blocks x 64 threads
__global__ void k_fix(const float* __restrict__ x, const float* __restrict__ wout,
                      const int* __restrict__ det,
                      const float* __restrict__ cw0, const float* __restrict__ cb0,
                      const float* __restrict__ cw1, const float* __restrict__ cb1,
                      const float* __restrict__ cw2, const float* __restrict__ cb2,
                      const float* __restrict__ cw3, const float* __restrict__ cb3,
                      float* __restrict__ out){
  int blk = blockIdx.x;
  int co = blk & 31;
  int bi = blk >> 5;
  int b = bi>>2, idx = bi&3;
  int cx = det[(b*S_+idx)*4+0], cy = det[(b*S_+idx)*4+1];
  if (!(cy>=2 && cy<H_-2 && cx>=2 && cx<W_-2)) return;   // uniform per block
  int ys = cy-2, xs = cx-2;  // in-bounds given validity
  int k = 2*idx+3, pad = idx+1, kk = k*k;
  const float* cw = idx==0?cw0: idx==1?cw1: idx==2?cw2:cw3;
  const float* cb = idx==0?cb0: idx==1?cb1: idx==2?cb2:cb3;
  __shared__ float reg[32*25];
  __shared__ float wl[32*81];
  int tid = threadIdx.x;
  for (int t=tid;t<800;t+=64){
    int ci=t/25, r=t%25, ry=r/5, rx=r%5;
    int g = idx*2 + (ci>>4), cg = ci&15;
    int bg = b*G_+g; int plane = bg*CG_+cg;
    int p = (ys+ry)*W_ + xs+rx;
    reg[t] = x[(size_t)plane*HW_+p]*sigf(wout[(size_t)bg*HW_+p]);
  }
  for (int t=tid;t<32*kk;t+=64) wl[t] = cw[co*32*kk + t];
  __syncthreads();
  // lanes 0..24: pixels, ci 0..15 ; lanes 25..49: same pixels, ci 16..31
  int pix = (tid<25)?tid:(tid-25);
  int half = (tid<25)?0:1;
  float acc = 0.f;
  if (tid < 50){
    int oy = pix/5, ox = pix%5;
    for (int ci=half*16; ci<half*16+16; ++ci){
      const float* wr = wl + ci*kk;
      const float* rr = reg + ci*25;
      #pragma unroll
      for (int iy=0; iy<5; ++iy){
        int ky = iy-oy+pad;
        if ((unsigned)ky >= (unsigned)k) continue;
        #pragma unroll
        for (int ix=0; ix<5; ++ix){
          int kx = ix-ox+pad;
          if ((unsigned)kx >= (unsigned)k) continue;
          acc += wr[ky*k+kx]*rr[iy*5+ix];
        }
      }
    }
  }
  float other = __shfl(acc, tid+25, 64);
  if (tid < 25){
    float tot = cb[co] + acc + other;
    int oy = pix/5, ox = pix%5;
    int g = idx*2 + (co>>4), cg = co&15;
    int bg = b*G_+g; int plane = bg*CG_+cg;
    int p = (ys+oy)*W_ + xs+ox;
    float xv = x[(size_t)plane*HW_+p];
    out[(size_t)(b*128 + cg*8 + g)*HW_+p] = xv + tot*sigf(tot);
  }
}

extern "C" void kernel_launch(void* const* d_in, const int* in_sizes, int n_in,
                              void* d_out, int out_size, void* d_ws, size_t ws_size,
                              hipStream_t stream){
  const float* x   = (const float*)d_in[0];
  const int*   det = (const int*)d_in[1];
  const float* w1  = (const float*)d_in[2];
  const float* b1  = (const float*)d_in[3];
  const float* w3  = (const float*)d_in[4];
  const float* b3  = (const float*)d_in[5];
  const float* gnw = (const float*)d_in[6];
  const float* gnb = (const float*)d_in[7];
  const float* cw0 = (const float*)d_in[8];  const float* cb0 = (const float*)d_in[9];
  const float* cw1 = (const float*)d_in[10]; const float* cb1 = (const float*)d_in[11];
  const float* cw2 = (const float*)d_in[12]; const float* cb2 = (const float*)d_in[13];
  const float* cw3 = (const float*)d_in[14]; const float* cb3 = (const float*)d_in[15];

  float* ws = (float*)d_ws;
  float* xh    = ws;                 // PC_*H_
  float* xw    = xh + PC_*H_;        // PC_*W_
  float* sh    = xw + PC_*W_;        // PC_*H_
  float* sw    = sh + PC_*H_;        // PC_*W_
  float* mu    = sw + PC_*W_;        // PC_
  float* rstd  = mu + PC_;           // PC_
  float* x21   = rstd + PC_;         // PC_
  float* alpha = x21 + PC_;          // PC_
  float* wsum  = alpha + PC_;        // NG_*144
  float* bsum  = wsum + NG_*144;     // NG_
  float* wconst= bsum + NG_;         // NG_
  float* wout  = wconst + NG_;       // NG_*HW_
  float* outp  = (float*)d_out;

  k_stats1<<<PC_,256,0,stream>>>(x, xh, xw);
  k_prep<<<NG_,256,0,stream>>>(x, xh, xw, w1,b1,w3,b3,gnb, sh,sw,x21,wsum,bsum);
  k_stats2<<<PC_,256,0,stream>>>(x, sh, sw, mu, rstd);
  k_coef<<<NG_,64,0,stream>>>(x21,gnw,gnb,mu,rstd,bsum,alpha,wconst);
  dim3 gw(NTILE_, NG_);   // 64 float4-slots per block; swizzled inside
  k_weights<<<gw,256,0,stream>>>(x, sh, sw, alpha, wsum, wconst, wout, outp);
  k_fix<<<B_*S_*32,64,0,stream>>>(x, wout, det, cw0,cb0,cw1,cb1,cw2,cb2,cw3,cb3, outp);
}